// Round 8
// baseline (1738.303 us; speedup 1.0000x reference)
//
#include <hip/hip_runtime.h>
#include <hip/hip_fp16.h>
#include <cstdint>
#include <cstddef>

#define NB 16
#define NC 256
#define NK 8
#define NN 16384
#define NSTAGE 10
#define FKAPPA 20.0f
#define NT 64              // n per tile
#define TPB 2              // tiles per block -> 128 n per block
#define NBLK 128           // blocks per batch (128 * 128 n = 16384)

// ---------------------------------------------------------------------------
// init: broadcast mu_in [C*K] -> mu_cur [B][C][K]
__global__ __launch_bounds__(256) void k_init_mu(const float* __restrict__ mu_in,
                                                 float* __restrict__ mu_cur) {
    int i = blockIdx.x * 256 + threadIdx.x;
    mu_cur[i] = mu_in[i & (NC * NK - 1)];
}

// ---------------------------------------------------------------------------
// Fused stage, atomic-free, 512 threads (8 waves), 2 blocks/CU -> 16 waves/CU.
// Per tile: batched 8x float4 x loads (deep vmcnt) -> fp16 LDS tile + fp32 dot
//           vs LDS mu; shfl-xor fold; per-wave partials dzp (no LDS atomics);
//           wave0 softmax sums dzp -> dz; phase2 thread=(c, n-half) register acc.
// End: non-atomic partial writes part[bx][nh][c][k], cspart[bx][k].
template <bool WRITE_Z>
__global__ __launch_bounds__(512, 4) void k_stage(const float* __restrict__ x,
                                                  const float* __restrict__ mu,
                                                  float* __restrict__ part,
                                                  float* __restrict__ cspart,
                                                  float* __restrict__ zraw) {
    const int b    = blockIdx.x >> 7;
    const int nt2  = blockIdx.x & (NBLK - 1);
    const int t    = threadIdx.x;
    const int lane = t & 63;
    const int wv   = t >> 6;          // 0..7

    __shared__ __align__(16) __half xt[NC][66];     // 33792 B
    __shared__ __align__(16) float  smu[NC * NK];   //  8192 B
    __shared__ __align__(16) float  dzp[8][NT][9];  // 18432 B (9-pad: bank-free)
    __shared__ __align__(16) float  dz[NT][12];     //  3072 B
    // total 63488 B -> 2 blocks/CU

    reinterpret_cast<float4*>(smu)[t] =
        reinterpret_cast<const float4*>(mu + (size_t)b * NC * NK)[t];  // 512 f4 = 2048 f

    const int nl = (lane & 15) * 4;   // n offset (float4 group)
    const int cg = lane >> 4;         // c sub-row 0..3
    const int c2 = t & 255;           // phase-2 c
    const int nh = t >> 8;            // phase-2 n-half (0/1)

    float a2[NK], csk[NK];
    #pragma unroll
    for (int k = 0; k < NK; k++) { a2[k] = 0.f; csk[k] = 0.f; }

    for (int g = 0; g < TPB; ++g) {
        const int n0 = (nt2 * TPB + g) * NT;
        __syncthreads();   // protects xt/dz/dzp reuse (and smu on first iter)

        // ---- phase 1: batched loads, then convert+dot
        const float* xp = x + (size_t)b * NC * NN + n0 + nl;
        float4 xv[8];
        #pragma unroll
        for (int ci = 0; ci < 8; ++ci)
            xv[ci] = *reinterpret_cast<const float4*>(xp + (size_t)(wv * 32 + ci * 4 + cg) * NN);

        float acc[4][NK];
        #pragma unroll
        for (int i = 0; i < 4; i++)
            #pragma unroll
            for (int k = 0; k < NK; k++) acc[i][k] = 0.f;

        #pragma unroll
        for (int ci = 0; ci < 8; ++ci) {
            const int c = wv * 32 + ci * 4 + cg;
            const float4 v = xv[ci];
            *reinterpret_cast<__half2*>(&xt[c][nl])     = __floats2half2_rn(v.x, v.y);
            *reinterpret_cast<__half2*>(&xt[c][nl + 2]) = __floats2half2_rn(v.z, v.w);
            const float4 m0 = *reinterpret_cast<const float4*>(&smu[c * NK]);
            const float4 m1 = *reinterpret_cast<const float4*>(&smu[c * NK + 4]);
            acc[0][0] += v.x * m0.x; acc[0][1] += v.x * m0.y; acc[0][2] += v.x * m0.z; acc[0][3] += v.x * m0.w;
            acc[0][4] += v.x * m1.x; acc[0][5] += v.x * m1.y; acc[0][6] += v.x * m1.z; acc[0][7] += v.x * m1.w;
            acc[1][0] += v.y * m0.x; acc[1][1] += v.y * m0.y; acc[1][2] += v.y * m0.z; acc[1][3] += v.y * m0.w;
            acc[1][4] += v.y * m1.x; acc[1][5] += v.y * m1.y; acc[1][6] += v.y * m1.z; acc[1][7] += v.y * m1.w;
            acc[2][0] += v.z * m0.x; acc[2][1] += v.z * m0.y; acc[2][2] += v.z * m0.z; acc[2][3] += v.z * m0.w;
            acc[2][4] += v.z * m1.x; acc[2][5] += v.z * m1.y; acc[2][6] += v.z * m1.z; acc[2][7] += v.z * m1.w;
            acc[3][0] += v.w * m0.x; acc[3][1] += v.w * m0.y; acc[3][2] += v.w * m0.z; acc[3][3] += v.w * m0.w;
            acc[3][4] += v.w * m1.x; acc[3][5] += v.w * m1.y; acc[3][6] += v.w * m1.z; acc[3][7] += v.w * m1.w;
        }

        // fold the 4 c-subrows within the wave (lanes ^16, ^32 share nl)
        #pragma unroll
        for (int m = 16; m <= 32; m <<= 1)
            #pragma unroll
            for (int i = 0; i < 4; i++)
                #pragma unroll
                for (int k = 0; k < NK; k++) acc[i][k] += __shfl_xor(acc[i][k], m, 64);

        if (lane < 16) {   // per-wave partial (sum over this wave's 32 c)
            #pragma unroll
            for (int i = 0; i < 4; i++)
                #pragma unroll
                for (int k = 0; k < NK; k++) dzp[wv][nl + i][k] = acc[i][k];
        }
        __syncthreads();

        // ---- softmax (wave 0, t = n): sum 8 wave-partials, softmax over k
        if (t < NT) {
            float l[NK];
            float mx = -1e30f;
            #pragma unroll
            for (int k = 0; k < NK; k++) {
                float s = dzp[0][t][k];
                #pragma unroll
                for (int w = 1; w < 8; ++w) s += dzp[w][t][k];
                l[k] = FKAPPA * s;
                mx = fmaxf(mx, l[k]);
            }
            float s = 0.f;
            #pragma unroll
            for (int k = 0; k < NK; k++) { l[k] = __expf(l[k] - mx); s += l[k]; }
            const float inv = 1.f / s;
            #pragma unroll
            for (int k = 0; k < NK; k++) { l[k] *= inv; dz[t][k] = l[k]; }
            if (WRITE_Z) {
                float* zp = zraw + ((size_t)b * NN + n0 + t) * NK;
                *reinterpret_cast<float4*>(zp)     = make_float4(l[0], l[1], l[2], l[3]);
                *reinterpret_cast<float4*>(zp + 4) = make_float4(l[4], l[5], l[6], l[7]);
            }
            #pragma unroll
            for (int off = 32; off > 0; off >>= 1)
                #pragma unroll
                for (int k = 0; k < NK; k++) l[k] += __shfl_down(l[k], off, 64);
            #pragma unroll
            for (int k = 0; k < NK; k++) csk[k] += l[k];    // lane 0 meaningful
        }
        __syncthreads();

        // ---- phase 2: thread = (c2, nh); 32 n per thread
        #pragma unroll 8
        for (int jj = 0; jj < 16; ++jj) {
            const int j = nh * 16 + jj;
            const __half2 xh = *reinterpret_cast<const __half2*>(&xt[c2][2 * j]);
            const float2 xf = __half22float2(xh);
            const float4 za0 = *reinterpret_cast<const float4*>(&dz[2 * j][0]);
            const float4 za1 = *reinterpret_cast<const float4*>(&dz[2 * j][4]);
            const float4 zb0 = *reinterpret_cast<const float4*>(&dz[2 * j + 1][0]);
            const float4 zb1 = *reinterpret_cast<const float4*>(&dz[2 * j + 1][4]);
            a2[0] += xf.x * za0.x + xf.y * zb0.x;
            a2[1] += xf.x * za0.y + xf.y * zb0.y;
            a2[2] += xf.x * za0.z + xf.y * zb0.z;
            a2[3] += xf.x * za0.w + xf.y * zb0.w;
            a2[4] += xf.x * za1.x + xf.y * zb1.x;
            a2[5] += xf.x * za1.y + xf.y * zb1.y;
            a2[6] += xf.x * za1.z + xf.y * zb1.z;
            a2[7] += xf.x * za1.w + xf.y * zb1.w;
        }
    }

    float* pp = part + (size_t)blockIdx.x * (2 * NC * NK) + (size_t)nh * (NC * NK) + c2 * NK;
    *reinterpret_cast<float4*>(pp)     = make_float4(a2[0], a2[1], a2[2], a2[3]);
    *reinterpret_cast<float4*>(pp + 4) = make_float4(a2[4], a2[5], a2[6], a2[7]);
    if (t == 0) {
        #pragma unroll
        for (int k = 0; k < NK; k++) cspart[blockIdx.x * NK + k] = csk[k];
    }
}

// ---------------------------------------------------------------------------
// reduce partials: num[b,ck] = sum over 256 per-block halves; colsum from cspart
// grid: NB*8 blocks, 256 threads
__global__ __launch_bounds__(256) void k_reduce(const float* __restrict__ part,
                                                const float* __restrict__ cspart,
                                                float* __restrict__ num,
                                                float* __restrict__ colsum) {
    const int b  = blockIdx.x >> 3;
    const int cg = blockIdx.x & 7;
    const int t  = threadIdx.x;
    const int ck = cg * 256 + t;

    float s = 0.f;
    const float* p = part + (size_t)b * NBLK * (2 * NC * NK) + ck;
    #pragma unroll 8
    for (int m = 0; m < 2 * NBLK; ++m) s += p[(size_t)m * (NC * NK)];
    num[b * (NC * NK) + ck] = s;

    __shared__ float cred[2][NK];
    if (cg == 0 && t < NBLK) {
        const float4 u0 = *reinterpret_cast<const float4*>(&cspart[(b * NBLK + t) * NK]);
        const float4 u1 = *reinterpret_cast<const float4*>(&cspart[(b * NBLK + t) * NK + 4]);
        float v[NK] = {u0.x, u0.y, u0.z, u0.w, u1.x, u1.y, u1.z, u1.w};
        #pragma unroll
        for (int off = 32; off > 0; off >>= 1)
            #pragma unroll
            for (int k = 0; k < NK; k++) v[k] += __shfl_down(v[k], off, 64);
        if ((t & 63) == 0)
            #pragma unroll
            for (int k = 0; k < NK; k++) cred[t >> 6][k] = v[k];
    }
    __syncthreads();
    if (cg == 0 && t < NK) colsum[b * NK + t] = cred[0][t] + cred[1][t];
}

// ---------------------------------------------------------------------------
// mu[b,c,k] = l2norm_c( num[b,c,k] / (1e-6+colsum[b,k]) ); grid NB, t = c
__global__ __launch_bounds__(256) void k_newmu(const float* __restrict__ num,
                                               const float* __restrict__ colsum,
                                               float* __restrict__ mu_out) {
    const int b = blockIdx.x;
    const int t = threadIdx.x;
    float inv[NK];
    #pragma unroll
    for (int k = 0; k < NK; k++) inv[k] = 1.f / (1e-6f + colsum[b * NK + k]);

    const float4 v0 = *reinterpret_cast<const float4*>(num + (size_t)b * NC * NK + t * NK);
    const float4 v1 = *reinterpret_cast<const float4*>(num + (size_t)b * NC * NK + t * NK + 4);
    float v[NK] = {v0.x * inv[0], v0.y * inv[1], v0.z * inv[2], v0.w * inv[3],
                   v1.x * inv[4], v1.y * inv[5], v1.z * inv[6], v1.w * inv[7]};

    float sq[NK];
    #pragma unroll
    for (int k = 0; k < NK; k++) sq[k] = v[k] * v[k];
    #pragma unroll
    for (int off = 32; off > 0; off >>= 1)
        #pragma unroll
        for (int k = 0; k < NK; k++) sq[k] += __shfl_down(sq[k], off, 64);

    __shared__ float red[4][NK];
    const int wave = t >> 6, lane = t & 63;
    if (lane == 0)
        #pragma unroll
        for (int k = 0; k < NK; k++) red[wave][k] = sq[k];
    __syncthreads();
    __shared__ float scale[NK];
    if (t < NK) {
        const float tot = red[0][t] + red[1][t] + red[2][t] + red[3][t];
        scale[t] = 1.f / (1e-6f + sqrtf(tot));
    }
    __syncthreads();
    #pragma unroll
    for (int k = 0; k < NK; k++) v[k] *= scale[k];
    *reinterpret_cast<float4*>(mu_out + (size_t)b * NC * NK + t * NK)     = make_float4(v[0], v[1], v[2], v[3]);
    *reinterpret_cast<float4*>(mu_out + (size_t)b * NC * NK + t * NK + 4) = make_float4(v[4], v[5], v[6], v[7]);
}

// ---------------------------------------------------------------------------
// out0[b,k,c] = mu[b,c,k]
__global__ __launch_bounds__(256) void k_write_mu(const float* __restrict__ mu,
                                                  float* __restrict__ out) {
    const int i = blockIdx.x * 256 + threadIdx.x;
    const int b = i >> 11, r = i & 2047;
    const int k = r >> 8, c = r & 255;
    out[i] = mu[(size_t)b * NC * NK + c * NK + k];
}

// in-place: out1[b,n,k] /= (1e-6 + colsum[b,k]); thread = 4-n group
__global__ __launch_bounds__(256) void k_write_z(const float* __restrict__ colsum,
                                                 float* __restrict__ out1) {
    const int i = blockIdx.x * 256 + threadIdx.x;   // 0 .. NB*NN/4-1
    const int b = i >> 12;
    const int n4 = (i & 4095) * 4;
    float inv[NK];
    #pragma unroll
    for (int k = 0; k < NK; k++) inv[k] = 1.f / (1e-6f + colsum[b * NK + k]);

    float4* p = reinterpret_cast<float4*>(out1 + ((size_t)b * NN + n4) * NK);
    #pragma unroll
    for (int j = 0; j < 4; ++j) {
        float4 a = p[2 * j], c = p[2 * j + 1];
        a.x *= inv[0]; a.y *= inv[1]; a.z *= inv[2]; a.w *= inv[3];
        c.x *= inv[4]; c.y *= inv[5]; c.z *= inv[6]; c.w *= inv[7];
        p[2 * j] = a; p[2 * j + 1] = c;
    }
}

// ---------------------------------------------------------------------------
extern "C" void kernel_launch(void* const* d_in, const int* in_sizes, int n_in,
                              void* d_out, int out_size, void* d_ws, size_t ws_size,
                              hipStream_t stream) {
    const float* x     = (const float*)d_in[0];   // [16,256,128,128]
    const float* mu_in = (const float*)d_in[1];   // [1,256,8]
    float* out  = (float*)d_out;                  // mu_f [16*8*256] ++ z_ [16*16384*8]
    float* out1 = out + NB * NK * NC;
    char* ws = (char*)d_ws;

    const size_t PART_BYTES = (size_t)NB * NBLK * 2 * NC * NK * 4;  // 33,554,432
    const size_t CSP_BYTES  = (size_t)NB * NBLK * NK * 4;           // 65,536
    const size_t NUM_BYTES  = (size_t)NB * NC * NK * 4;             // 131,072
    const size_t CS_BYTES   = (size_t)NB * NK * 4;                  // 512

    float* part   = (float*)ws;
    float* cspart = (float*)(ws + PART_BYTES);
    float* num    = (float*)(ws + PART_BYTES + CSP_BYTES);
    float* colsum = (float*)(ws + PART_BYTES + CSP_BYTES + NUM_BYTES);
    float* mu_a   = (float*)(ws + PART_BYTES + CSP_BYTES + NUM_BYTES + CS_BYTES);

    k_init_mu<<<NB * NC * NK / 256, 256, 0, stream>>>(mu_in, mu_a);

    for (int s = 0; s < NSTAGE; ++s) {
        if (s == NSTAGE - 1)
            k_stage<true><<<NB * NBLK, 512, 0, stream>>>(x, mu_a, part, cspart, out1);
        else
            k_stage<false><<<NB * NBLK, 512, 0, stream>>>(x, mu_a, part, cspart, out1);
        k_reduce<<<NB * 8, 256, 0, stream>>>(part, cspart, num, colsum);
        k_newmu<<<NB, 256, 0, stream>>>(num, colsum, mu_a);
    }

    k_write_mu<<<NB * NK * NC / 256, 256, 0, stream>>>(mu_a, out);
    k_write_z<<<NB * NN / 4 / 256, 256, 0, stream>>>(colsum, out1);
}

// Round 11
// 1382.224 us; speedup vs baseline: 1.2576x; 1.2576x over previous
//
#include <hip/hip_runtime.h>
#include <hip/hip_fp16.h>
#include <cstdint>
#include <cstddef>

#define NB 16
#define NC 256
#define NK 8
#define NN 16384
#define NSTAGE 10
#define FKAPPA 20.0f
#define NT 64              // n per tile
#define TPB 2              // tiles per block -> 128 n per block
#define NBLK 128           // blocks per batch (128 * 128 n = 16384)

// ---------------------------------------------------------------------------
// init: broadcast mu_in [C*K] -> mu_cur [B][C][K]
__global__ __launch_bounds__(256) void k_init_mu(const float* __restrict__ mu_in,
                                                 float* __restrict__ mu_cur) {
    int i = blockIdx.x * 256 + threadIdx.x;
    mu_cur[i] = mu_in[i & (NC * NK - 1)];
}

// ---------------------------------------------------------------------------
// Fused stage, atomic-free, fully-parallel softmax. 512 threads (8 waves).
// Per tile:
//   P1: batched 8x float4 x loads -> fp16 xt LDS + fp32 dot vs LDS mu;
//       shfl-xor fold -> per-wave partials dzp[w][n][k] (no LDS atomics).
//   SM: thread=(n,k) [512 = 64x8]: sum 8 partials, shfl_xor(1,2,4) row
//       max/sum, z -> dz[n][k]; colsum kept in a register accumulator.
//   P2: thread=(c, n-half): batched conflict-free half2 xt reads + b128
//       broadcast dz reads; 8 register accumulators.
// End: non-atomic partial writes part[bx][nh][c][k], cspart[bx][k].
template <bool WRITE_Z>
__global__ __launch_bounds__(512, 4) void k_stage(const float* __restrict__ x,
                                                  const float* __restrict__ mu,
                                                  float* __restrict__ part,
                                                  float* __restrict__ cspart,
                                                  float* __restrict__ zraw) {
    const int b    = blockIdx.x >> 7;
    const int nt2  = blockIdx.x & (NBLK - 1);
    const int t    = threadIdx.x;
    const int lane = t & 63;
    const int wv   = t >> 6;          // 0..7

    __shared__ __align__(16) __half xt[NC][66];     // 33792 B (66: free W+R banks)
    __shared__ __align__(16) float  smu[NC * NK];   //  8192 B
    __shared__ __align__(16) float  dzp[8][NT][9];  // 18432 B (9-pad)
    __shared__ __align__(16) float  dz[NT][NK];     //  2048 B
    __shared__ float csred[8][NK];                  //   256 B

    reinterpret_cast<float4*>(smu)[t] =
        reinterpret_cast<const float4*>(mu + (size_t)b * NC * NK)[t];

    const int nl = (lane & 15) * 4;   // P1: n offset (float4 group)
    const int cg = lane >> 4;         // P1: c sub-row 0..3
    const int sn = t >> 3;            // SM: n (0..63)
    const int sk = t & 7;             // SM: k (0..7)
    const int c2 = t & 255;           // P2: c
    const int nh = t >> 8;            // P2: n-half (0/1)

    float a2[NK];
    #pragma unroll
    for (int k = 0; k < NK; k++) a2[k] = 0.f;
    float csacc = 0.f;

    for (int g = 0; g < TPB; ++g) {
        const int n0 = (nt2 * TPB + g) * NT;
        __syncthreads();   // protects xt/dz/dzp reuse (and smu on first iter)

        // ---- P1: batched loads, then convert+dot
        const float* xp = x + (size_t)b * NC * NN + n0 + nl;
        float4 xv[8];
        #pragma unroll
        for (int ci = 0; ci < 8; ++ci)
            xv[ci] = *reinterpret_cast<const float4*>(xp + (size_t)(wv * 32 + ci * 4 + cg) * NN);

        float acc[4][NK];
        #pragma unroll
        for (int i = 0; i < 4; i++)
            #pragma unroll
            for (int k = 0; k < NK; k++) acc[i][k] = 0.f;

        #pragma unroll
        for (int ci = 0; ci < 8; ++ci) {
            const int c = wv * 32 + ci * 4 + cg;
            const float4 v = xv[ci];
            *reinterpret_cast<__half2*>(&xt[c][nl])     = __floats2half2_rn(v.x, v.y);
            *reinterpret_cast<__half2*>(&xt[c][nl + 2]) = __floats2half2_rn(v.z, v.w);
            const float4 m0 = *reinterpret_cast<const float4*>(&smu[c * NK]);
            const float4 m1 = *reinterpret_cast<const float4*>(&smu[c * NK + 4]);
            acc[0][0] += v.x * m0.x; acc[0][1] += v.x * m0.y; acc[0][2] += v.x * m0.z; acc[0][3] += v.x * m0.w;
            acc[0][4] += v.x * m1.x; acc[0][5] += v.x * m1.y; acc[0][6] += v.x * m1.z; acc[0][7] += v.x * m1.w;
            acc[1][0] += v.y * m0.x; acc[1][1] += v.y * m0.y; acc[1][2] += v.y * m0.z; acc[1][3] += v.y * m0.w;
            acc[1][4] += v.y * m1.x; acc[1][5] += v.y * m1.y; acc[1][6] += v.y * m1.z; acc[1][7] += v.y * m1.w;
            acc[2][0] += v.z * m0.x; acc[2][1] += v.z * m0.y; acc[2][2] += v.z * m0.z; acc[2][3] += v.z * m0.w;
            acc[2][4] += v.z * m1.x; acc[2][5] += v.z * m1.y; acc[2][6] += v.z * m1.z; acc[2][7] += v.z * m1.w;
            acc[3][0] += v.w * m0.x; acc[3][1] += v.w * m0.y; acc[3][2] += v.w * m0.z; acc[3][3] += v.w * m0.w;
            acc[3][4] += v.w * m1.x; acc[3][5] += v.w * m1.y; acc[3][6] += v.w * m1.z; acc[3][7] += v.w * m1.w;
        }

        // fold the 4 c-subrows within the wave (lanes ^16, ^32 share nl)
        #pragma unroll
        for (int m = 16; m <= 32; m <<= 1)
            #pragma unroll
            for (int i = 0; i < 4; i++)
                #pragma unroll
                for (int k = 0; k < NK; k++) acc[i][k] += __shfl_xor(acc[i][k], m, 64);

        if (lane < 16) {   // per-wave partial (sum over this wave's 32 c)
            #pragma unroll
            for (int i = 0; i < 4; i++)
                #pragma unroll
                for (int k = 0; k < NK; k++) dzp[wv][nl + i][k] = acc[i][k];
        }
        __syncthreads();

        // ---- SM: fully parallel softmax, thread = (sn, sk)
        {
            float s = dzp[0][sn][sk];
            #pragma unroll
            for (int w = 1; w < 8; ++w) s += dzp[w][sn][sk];   // independent reads
            const float l = FKAPPA * s;
            float mx = l;
            #pragma unroll
            for (int m = 1; m < 8; m <<= 1) mx = fmaxf(mx, __shfl_xor(mx, m, 64));
            const float e = __expf(l - mx);
            float es = e;
            #pragma unroll
            for (int m = 1; m < 8; m <<= 1) es += __shfl_xor(es, m, 64);
            const float zv = e / es;
            dz[sn][sk] = zv;
            if (WRITE_Z) zraw[((size_t)b * NN + n0 + sn) * NK + sk] = zv;  // coalesced
            csacc += zv;
        }
        __syncthreads();

        // ---- P2: thread = (c2, nh); 32 n per thread, batched reads
        #pragma unroll
        for (int grp = 0; grp < 4; ++grp) {
            __half2 h[4];
            #pragma unroll
            for (int q = 0; q < 4; ++q)
                h[q] = *reinterpret_cast<const __half2*>(&xt[c2][nh * 32 + grp * 8 + q * 2]);
            #pragma unroll
            for (int q = 0; q < 4; ++q) {
                const int r = nh * 32 + grp * 8 + q * 2;       // n-pair (r, r+1)
                const float2 xf = __half22float2(h[q]);
                const float4 za0 = *reinterpret_cast<const float4*>(&dz[r][0]);
                const float4 za1 = *reinterpret_cast<const float4*>(&dz[r][4]);
                const float4 zb0 = *reinterpret_cast<const float4*>(&dz[r + 1][0]);
                const float4 zb1 = *reinterpret_cast<const float4*>(&dz[r + 1][4]);
                a2[0] += xf.x * za0.x + xf.y * zb0.x;
                a2[1] += xf.x * za0.y + xf.y * zb0.y;
                a2[2] += xf.x * za0.z + xf.y * zb0.z;
                a2[3] += xf.x * za0.w + xf.y * zb0.w;
                a2[4] += xf.x * za1.x + xf.y * zb1.x;
                a2[5] += xf.x * za1.y + xf.y * zb1.y;
                a2[6] += xf.x * za1.z + xf.y * zb1.z;
                a2[7] += xf.x * za1.w + xf.y * zb1.w;
            }
        }
    }

    // colsum: fold lanes with same sk (strides 8,16,32), then cross-wave via LDS
    float cs = csacc;
    #pragma unroll
    for (int m = 8; m < 64; m <<= 1) cs += __shfl_xor(cs, m, 64);
    if (lane < 8) csred[wv][lane] = cs;

    float* pp = part + (size_t)blockIdx.x * (2 * NC * NK) + (size_t)nh * (NC * NK) + c2 * NK;
    *reinterpret_cast<float4*>(pp)     = make_float4(a2[0], a2[1], a2[2], a2[3]);
    *reinterpret_cast<float4*>(pp + 4) = make_float4(a2[4], a2[5], a2[6], a2[7]);

    __syncthreads();
    if (t < NK) {
        float s = 0.f;
        #pragma unroll
        for (int w = 0; w < 8; ++w) s += csred[w][t];
        cspart[blockIdx.x * NK + t] = s;
    }
}

// ---------------------------------------------------------------------------
// reduce partials: num[b,ck] = sum over 256 per-block halves; colsum from cspart
// grid: NB*8 blocks, 256 threads
__global__ __launch_bounds__(256) void k_reduce(const float* __restrict__ part,
                                                const float* __restrict__ cspart,
                                                float* __restrict__ num,
                                                float* __restrict__ colsum) {
    const int b  = blockIdx.x >> 3;
    const int cg = blockIdx.x & 7;
    const int t  = threadIdx.x;
    const int ck = cg * 256 + t;

    float s = 0.f;
    const float* p = part + (size_t)b * NBLK * (2 * NC * NK) + ck;
    #pragma unroll 8
    for (int m = 0; m < 2 * NBLK; ++m) s += p[(size_t)m * (NC * NK)];
    num[b * (NC * NK) + ck] = s;

    __shared__ float cred[2][NK];
    if (cg == 0 && t < NBLK) {
        const float4 u0 = *reinterpret_cast<const float4*>(&cspart[(b * NBLK + t) * NK]);
        const float4 u1 = *reinterpret_cast<const float4*>(&cspart[(b * NBLK + t) * NK + 4]);
        float v[NK] = {u0.x, u0.y, u0.z, u0.w, u1.x, u1.y, u1.z, u1.w};
        #pragma unroll
        for (int off = 32; off > 0; off >>= 1)
            #pragma unroll
            for (int k = 0; k < NK; k++) v[k] += __shfl_down(v[k], off, 64);
        if ((t & 63) == 0)
            #pragma unroll
            for (int k = 0; k < NK; k++) cred[t >> 6][k] = v[k];
    }
    __syncthreads();
    if (cg == 0 && t < NK) colsum[b * NK + t] = cred[0][t] + cred[1][t];
}

// ---------------------------------------------------------------------------
// mu[b,c,k] = l2norm_c( num[b,c,k] / (1e-6+colsum[b,k]) ); grid NB, t = c
__global__ __launch_bounds__(256) void k_newmu(const float* __restrict__ num,
                                               const float* __restrict__ colsum,
                                               float* __restrict__ mu_out) {
    const int b = blockIdx.x;
    const int t = threadIdx.x;
    float inv[NK];
    #pragma unroll
    for (int k = 0; k < NK; k++) inv[k] = 1.f / (1e-6f + colsum[b * NK + k]);

    const float4 v0 = *reinterpret_cast<const float4*>(num + (size_t)b * NC * NK + t * NK);
    const float4 v1 = *reinterpret_cast<const float4*>(num + (size_t)b * NC * NK + t * NK + 4);
    float v[NK] = {v0.x * inv[0], v0.y * inv[1], v0.z * inv[2], v0.w * inv[3],
                   v1.x * inv[4], v1.y * inv[5], v1.z * inv[6], v1.w * inv[7]};

    float sq[NK];
    #pragma unroll
    for (int k = 0; k < NK; k++) sq[k] = v[k] * v[k];
    #pragma unroll
    for (int off = 32; off > 0; off >>= 1)
        #pragma unroll
        for (int k = 0; k < NK; k++) sq[k] += __shfl_down(sq[k], off, 64);

    __shared__ float red[4][NK];
    const int wave = t >> 6, lane = t & 63;
    if (lane == 0)
        #pragma unroll
        for (int k = 0; k < NK; k++) red[wave][k] = sq[k];
    __syncthreads();
    __shared__ float scale[NK];
    if (t < NK) {
        const float tot = red[0][t] + red[1][t] + red[2][t] + red[3][t];
        scale[t] = 1.f / (1e-6f + sqrtf(tot));
    }
    __syncthreads();
    #pragma unroll
    for (int k = 0; k < NK; k++) v[k] *= scale[k];
    *reinterpret_cast<float4*>(mu_out + (size_t)b * NC * NK + t * NK)     = make_float4(v[0], v[1], v[2], v[3]);
    *reinterpret_cast<float4*>(mu_out + (size_t)b * NC * NK + t * NK + 4) = make_float4(v[4], v[5], v[6], v[7]);
}

// ---------------------------------------------------------------------------
// out0[b,k,c] = mu[b,c,k]
__global__ __launch_bounds__(256) void k_write_mu(const float* __restrict__ mu,
                                                  float* __restrict__ out) {
    const int i = blockIdx.x * 256 + threadIdx.x;
    const int b = i >> 11, r = i & 2047;
    const int k = r >> 8, c = r & 255;
    out[i] = mu[(size_t)b * NC * NK + c * NK + k];
}

// in-place: out1[b,n,k] /= (1e-6 + colsum[b,k]); thread = 4-n group
__global__ __launch_bounds__(256) void k_write_z(const float* __restrict__ colsum,
                                                 float* __restrict__ out1) {
    const int i = blockIdx.x * 256 + threadIdx.x;   // 0 .. NB*NN/4-1
    const int b = i >> 12;
    const int n4 = (i & 4095) * 4;
    float inv[NK];
    #pragma unroll
    for (int k = 0; k < NK; k++) inv[k] = 1.f / (1e-6f + colsum[b * NK + k]);

    float4* p = reinterpret_cast<float4*>(out1 + ((size_t)b * NN + n4) * NK);
    #pragma unroll
    for (int j = 0; j < 4; ++j) {
        float4 a = p[2 * j], c = p[2 * j + 1];
        a.x *= inv[0]; a.y *= inv[1]; a.z *= inv[2]; a.w *= inv[3];
        c.x *= inv[4]; c.y *= inv[5]; c.z *= inv[6]; c.w *= inv[7];
        p[2 * j] = a; p[2 * j + 1] = c;
    }
}

// ---------------------------------------------------------------------------
extern "C" void kernel_launch(void* const* d_in, const int* in_sizes, int n_in,
                              void* d_out, int out_size, void* d_ws, size_t ws_size,
                              hipStream_t stream) {
    const float* x     = (const float*)d_in[0];   // [16,256,128,128]
    const float* mu_in = (const float*)d_in[1];   // [1,256,8]
    float* out  = (float*)d_out;                  // mu_f [16*8*256] ++ z_ [16*16384*8]
    float* out1 = out + NB * NK * NC;
    char* ws = (char*)d_ws;

    const size_t PART_BYTES = (size_t)NB * NBLK * 2 * NC * NK * 4;  // 33,554,432
    const size_t CSP_BYTES  = (size_t)NB * NBLK * NK * 4;           // 65,536
    const size_t NUM_BYTES  = (size_t)NB * NC * NK * 4;             // 131,072
    const size_t CS_BYTES   = (size_t)NB * NK * 4;                  // 512

    float* part   = (float*)ws;
    float* cspart = (float*)(ws + PART_BYTES);
    float* num    = (float*)(ws + PART_BYTES + CSP_BYTES);
    float* colsum = (float*)(ws + PART_BYTES + CSP_BYTES + NUM_BYTES);
    float* mu_a   = (float*)(ws + PART_BYTES + CSP_BYTES + NUM_BYTES + CS_BYTES);

    k_init_mu<<<NB * NC * NK / 256, 256, 0, stream>>>(mu_in, mu_a);

    for (int s = 0; s < NSTAGE; ++s) {
        if (s == NSTAGE - 1)
            k_stage<true><<<NB * NBLK, 512, 0, stream>>>(x, mu_a, part, cspart, out1);
        else
            k_stage<false><<<NB * NBLK, 512, 0, stream>>>(x, mu_a, part, cspart, out1);
        k_reduce<<<NB * 8, 256, 0, stream>>>(part, cspart, num, colsum);
        k_newmu<<<NB, 256, 0, stream>>>(num, colsum, mu_a);
    }

    k_write_mu<<<NB * NK * NC / 256, 256, 0, stream>>>(mu_a, out);
    k_write_z<<<NB * NN / 4 / 256, 256, 0, stream>>>(colsum, out1);
}